// Round 4
// baseline (182.151 us; speedup 1.0000x reference)
//
#include <hip/hip_runtime.h>
#include <hip/hip_bf16.h>

// Problem constants (B=8192, D=128 from reference setup_inputs)
constexpr int Bh = 8192;
constexpr int Nn = 16384;   // 2*B
constexpr int Dd = 128;
constexpr float EPS = 1e-8f;
constexpr float LN2 = 0.69314718056f;

constexpr int K_TILES = 8;          // tiles per block
constexpr int N_TILES = 8256;       // 128x128 upper-tri tiles (incl diag): 128*129/2
constexpr int N_BLOCKS = N_TILES / K_TILES;   // 1032, exact

typedef short bf16x8 __attribute__((ext_vector_type(8)));
typedef float f32x4 __attribute__((ext_vector_type(4)));

// ---- Kernel 1: fp32 -> bf16, scaled by sqrt(2*log2e) so MFMA dot == sim/tau*log2e ----
__global__ __launch_bounds__(256) void convert_kernel(const float4* __restrict__ za,
                                                      const float4* __restrict__ zb,
                                                      ushort* __restrict__ z,
                                                      float* __restrict__ rowsum,
                                                      float* __restrict__ out) {
    const int t = blockIdx.x * 256 + threadIdx.x;        // 0 .. 524287
    constexpr int Q = (Bh * Dd) / 4;                     // 262144 float4 per input
    const float SCL = 1.69864363f;                       // sqrt(2 * 1.4426950409)
    float4 v = (t < Q) ? za[t] : zb[t - Q];
    union { ushort4 u4; __hip_bfloat16 h[4]; } cv;
    cv.h[0] = __float2bfloat16(v.x * SCL);
    cv.h[1] = __float2bfloat16(v.y * SCL);
    cv.h[2] = __float2bfloat16(v.z * SCL);
    cv.h[3] = __float2bfloat16(v.w * SCL);
    ((ushort4*)z)[t] = cv.u4;
    if (t < Nn) rowsum[t] = 0.f;
    if (t == 0) out[0] = 0.f;          // finalize accumulates via atomics
}

// tile index g -> row tile t (128-row granularity): largest t with cum(t)=t*(257-t)/2 <= g
__device__ __forceinline__ int row_tile_of(int g) {
    int t = (int)((257.0f - sqrtf(66049.0f - 8.0f * (float)g)) * 0.5f);
    t = t < 0 ? 0 : (t > 127 ? 127 : t);
    while (t * (257 - t) / 2 > g) --t;
    while ((t + 1) * (256 - t) / 2 <= g) ++t;
    return t;
}

// row-credit flush: reduce rs over the 16 col-lanes, one atomic per row (log2 domain)
__device__ __forceinline__ void flush_rs(float* __restrict__ rowsum, int rowW,
                                         float (&rs)[4], int q, int c) {
#pragma unroll
    for (int r = 0; r < 4; ++r) {
        float v = rs[r];
        v += __shfl_xor(v, 1);
        v += __shfl_xor(v, 2);
        v += __shfl_xor(v, 4);
        v += __shfl_xor(v, 8);
        if (c == 0) atomicAdd(&rowsum[rowW + q * 4 + r], v);
        rs[r] = 0.f;
    }
}

// Stage one 128x128 bf16 B-tile (32 KB) into LDS via global_load_lds width-16.
// LDS layout is XOR-swizzled: phys (r, u16) holds logical (r, u16 ^ (r&15)).
// global_load_lds writes linearly (wave base + lane*16), so the swizzle is
// applied by permuting the GLOBAL source address per lane (m173 pattern).
// ds_read_b128 fragment reads are then bank-conflict-free (8 words/bank).
// 8 waves x 4 chunks of 1 KB = 32 KB.
__device__ __forceinline__ void stage_tile(const ushort* __restrict__ z, ushort* lbuf,
                                           int C0, int wave, int lane) {
#pragma unroll
    for (int i = 0; i < 4; ++i) {
        const int chunk = wave * 4 + i;              // 32 chunks of 1 KB
        const int r = (chunk << 2) + (lane >> 4);    // row 0..127 (one col of z)
        const int bl = ((lane & 15) ^ (r & 15)) << 4;  // swizzled byte-in-row
        const char* gp = (const char*)z + (((size_t)(C0 + r)) << 8) + bl;
        ushort* lp = lbuf + (chunk << 9);            // wave-uniform LDS base
        __builtin_amdgcn_global_load_lds((const __attribute__((address_space(1))) void*)gp,
                                         (__attribute__((address_space(3))) void*)lp,
                                         16, 0, 0);
    }
}

// ---- Kernel 2: symmetric upper-triangle at 128x128 granularity.
// R4: 8 waves/block (512 thr), wave owns 16 rows -> 4 waves/SIMD at the same
// 64 KB LDS dbuf (2 blocks/CU). R3 showed the VALU+trans epilogue is ~10x the
// MFMA work and VALUBusy stalled at 48% with 2 waves/SIMD -> latency-bound;
// this doubles TLP. Col credits now pre-reduced in LDS (colbuf, ds_add_f32),
// flushed one tile late by 128 threads -> 8x fewer global atomics and no
// per-address serialization growth. Stage issued BEFORE compute so the
// per-tile barrier drain finds all VMEM ops a full tile old.
__global__ __launch_bounds__(512) void main_kernel(const ushort* __restrict__ z,
                                                   float* __restrict__ rowsum,
                                                   float* __restrict__ pospair) {
    __shared__ ushort ldsb[2][16384];     // 2 x 32 KB B-tile double buffer
    __shared__ float colbuf[2][128];      // per-tile col-credit accumulator

    const int tid = threadIdx.x;
    const int wave = tid >> 6;
    const int lane = tid & 63;
    const int q = lane >> 4;        // quad: 0..3
    const int c = lane & 15;        // 0..15
    const int g0 = blockIdx.x * K_TILES;

    int tr = row_tile_of(g0);
    int ct = tr + (g0 - tr * (257 - tr) / 2);

    if (tid < 256) colbuf[tid >> 7][tid & 127] = 0.f;

    // per-lane swizzled LDS fragment offsets: logical 16B-unit (q+4kt) in row c
    int O[4];
#pragma unroll
    for (int kt = 0; kt < 4; ++kt) O[kt] = (c << 8) + ((((q + 4 * kt) ^ c)) << 4);

    bf16x8 afrag[4];
    float rs[4] = {0.f, 0.f, 0.f, 0.f};

    int C0P = 0;
    bool flushP = false;
    int cur_tr = -1, rowW = 0, cur = 0;

    stage_tile(z, &ldsb[0][0], ct << 7, wave, lane);
    __syncthreads();      // also orders colbuf init before any ds_add

    for (int j = 0; j < K_TILES; ++j) {
        const int pcur = j & 1;               // this tile's colbuf
        const int C0 = ct << 7;
        const bool diag = (ct == tr);

        if (tr != cur_tr) {                 // row-panel change: flush + reload A
            if (cur_tr >= 0) flush_rs(rowsum, rowW, rs, q, c);
            cur_tr = tr;
            rowW = (tr << 7) + wave * 16;   // this wave's 16-row base
            const ushort* ap = z + (size_t)(rowW + c) * Dd;
#pragma unroll
            for (int kt = 0; kt < 4; ++kt)
                afrag[kt] = *(const bf16x8*)(ap + kt * 32 + q * 8);
        }

        // flush previous tile's col credits (LDS-reduced), one tile deferred so
        // the global atomics are a full tile old at the next barrier drain.
        // Zeroing here is safe: next writes to colbuf[pcur^1] are tile j+1's
        // ds_adds, which happen after this tile's end barrier.
        if (flushP) {
            if (tid < 128) {
                atomicAdd(&rowsum[C0P + tid], colbuf[pcur ^ 1][tid]);
                colbuf[pcur ^ 1][tid] = 0.f;
            }
            flushP = false;
        }

        // next tile coords + prefetch-stage into the other buffer
        int trN = tr, ctN = ct + 1;
        if (ctN == 128) { trN = tr + 1; ctN = trN; }
        if (j + 1 < K_TILES) stage_tile(z, &ldsb[cur ^ 1][0], ctN << 7, wave, lane);

        const char* lb = (const char*)&ldsb[cur][0];

#pragma unroll
        for (int st = 0; st < 8; ++st) {
            bf16x8 bcur[4];
#pragma unroll
            for (int kt = 0; kt < 4; ++kt)
                bcur[kt] = *(const bf16x8*)(lb + O[kt] + st * 4096);

            f32x4 acc = {0.f, 0.f, 0.f, 0.f};
#pragma unroll
            for (int kt = 0; kt < 4; ++kt)
                acc = __builtin_amdgcn_mfma_f32_16x16x32_bf16(afrag[kt], bcur[kt], acc, 0, 0, 0);

            const int gc0 = C0 + st * 16;
            const int R = rowW;
            float sp[4];
#pragma unroll
            for (int r = 0; r < 4; ++r) {
                float u = acc[r];
                // softplus in log2 domain: max(u,0) + log2(1 + 2^-|u|)
                float e = __builtin_amdgcn_exp2f(-fabsf(u));
                sp[r] = fmaxf(u, 0.f) + __builtin_amdgcn_logf(1.f + e);
            }
            if (diag && gc0 == R) {               // zero self-similarity
#pragma unroll
                for (int r = 0; r < 4; ++r)
                    if (c == q * 4 + r) sp[r] = 0.f;
            }
            if (gc0 == (R ^ Bh)) {                // positive-pair subtile (rows<8192)
#pragma unroll
                for (int r = 0; r < 4; ++r)
                    if (c == q * 4 + r) pospair[R + q * 4 + r] = sp[r];
            }
#pragma unroll
            for (int r = 0; r < 4; ++r) rs[r] += sp[r];
            if (!diag) {    // col credit: reduce over q-groups, ds_add into colbuf
                float v = (sp[0] + sp[1]) + (sp[2] + sp[3]);
                v += __shfl_xor(v, 16);
                v += __shfl_xor(v, 32);
                if (lane < 16) atomicAdd(&colbuf[pcur][st * 16 + c], v);
            }
        }

        if (!diag) { C0P = C0; flushP = true; }

        __syncthreads();        // drains vmcnt(0): stage + atomics all a tile old
        cur ^= 1;
        tr = trN;
        ct = ctN;
    }

    // final colbuf flush (loop's last __syncthreads ordered the ds_adds)
    if (flushP && tid < 128)
        atomicAdd(&rowsum[C0P + tid], colbuf[(K_TILES - 1) & 1][tid]);
    if (cur_tr >= 0) flush_rs(rowsum, rowW, rs, q, c);
}

// ---- Kernel 3: final loss (log2-domain sums back via ln2), 16 blocks x 1024 ----
__global__ __launch_bounds__(1024) void finalize_kernel(const float* __restrict__ rowsum,
                                                        const float* __restrict__ pospair,
                                                        float* __restrict__ out) {
    __shared__ float red[16];
    const int i = blockIdx.x * 1024 + threadIdx.x;   // 16*1024 == Nn exactly
    float denom = fmaxf(LN2 * rowsum[i], EPS);
    float sp = fmaxf(LN2 * pospair[i & (Bh - 1)], EPS);   // pospair[i]==pospair[i^B]
    float acc = __logf(sp) - __logf(denom);
#pragma unroll
    for (int m = 1; m < 64; m <<= 1) acc += __shfl_xor(acc, m);
    if ((threadIdx.x & 63) == 0) red[threadIdx.x >> 6] = acc;
    __syncthreads();
    if (threadIdx.x < 16) {
        float v = red[threadIdx.x];
        v += __shfl_xor(v, 1);
        v += __shfl_xor(v, 2);
        v += __shfl_xor(v, 4);
        v += __shfl_xor(v, 8);
        if (threadIdx.x == 0) atomicAdd(out, -v / (float)Nn);
    }
}

extern "C" void kernel_launch(void* const* d_in, const int* in_sizes, int n_in,
                              void* d_out, int out_size, void* d_ws, size_t ws_size,
                              hipStream_t stream) {
    const float* za = (const float*)d_in[0];
    const float* zb = (const float*)d_in[1];

    // workspace layout: z_bf16 (4 MB) | rowsum (64 KB) | pospair (32 KB used)
    ushort* z = (ushort*)d_ws;
    float* rowsum = (float*)((char*)d_ws + (size_t)Nn * Dd * 2);
    float* pospair = rowsum + Nn;
    float* out = (float*)d_out;

    convert_kernel<<<2048, 256, 0, stream>>>((const float4*)za, (const float4*)zb, z, rowsum, out);
    main_kernel<<<N_BLOCKS, 512, 0, stream>>>(z, rowsum, pospair);
    finalize_kernel<<<16, 1024, 0, stream>>>(rowsum, pospair, out);
}